// Round 6
// baseline (653.177 us; speedup 1.0000x reference)
//
#include <hip/hip_runtime.h>
#include <hip/hip_bf16.h>

// GraphMatchingLayer, round 6:
//  - k_scatter now stores int2{e, col} at the CSR slot (col read COALESCED
//    there) -> edge kernel's random ei[E+e] chain-load is gone.
//  - k_edge4: one wave per node, lane = channel, chunk-of-4 software pipeline:
//    4 independent V-row loads in flight, ea rows via wave-uniform s_load.
//  - k_prep2 / k_node2 / CSR scan unchanged.

#define TPB 256

#define SEG_G(SRC, NCH, KB, W, ACC)                                     \
  for (int kc_ = 0; kc_ < (NCH); ++kc_) {                               \
    const float4 a_ = ((const float4*)(SRC))[kc_];                      \
    const float av_[4] = {a_.x, a_.y, a_.z, a_.w};                      \
    _Pragma("unroll")                                                   \
    for (int j_ = 0; j_ < 4; ++j_) {                                    \
      const float ak_ = av_[j_];                                        \
      const float* wr_ = (W) + ((KB) + kc_ * 4 + j_) * 64;              \
      _Pragma("unroll")                                                 \
      for (int cc_ = 0; cc_ < 64; ++cc_)                                \
        ACC[cc_] = fmaf(ak_, wr_[cc_], ACC[cc_]);                       \
    }                                                                   \
  }

#define SEGH(W, KB, SRCEXPR, ACC, HCOL)                                 \
  _Pragma("unroll")                                                     \
  for (int q_ = 0; q_ < 4; ++q_) {                                      \
    _Pragma("unroll")                                                   \
    for (int kk_ = 0; kk_ < 16; ++kk_)                                  \
      (HCOL)[kk_ * 257] = (SRCEXPR);                                    \
    for (int kk_ = 0; kk_ < 16; ++kk_) {                                \
      const float ak_ = (HCOL)[kk_ * 257];                              \
      const float* wr_ = (W) + ((KB) + q_ * 16 + kk_) * 64;             \
      _Pragma("unroll")                                                 \
      for (int cc_ = 0; cc_ < 64; ++cc_)                                \
        ACC[cc_] = fmaf(ak_, wr_[cc_], ACC[cc_]);                       \
    }                                                                   \
  }

// ---------------- CSR build ----------------

__global__ __launch_bounds__(TPB)
void k_hist(const int* __restrict__ ei, int* __restrict__ deg, int E) {
  int e = blockIdx.x * TPB + threadIdx.x;
  if (e < E) atomicAdd(&deg[ei[e]], 1);
}

__global__ __launch_bounds__(TPB)
void k_red(const int* __restrict__ deg, int* __restrict__ bsum, int N) {
  __shared__ int s[TPB];
  const int tid = threadIdx.x;
  const int g = (blockIdx.x * TPB + tid) * 4;
  int v = 0;
  #pragma unroll
  for (int j = 0; j < 4; ++j) if (g + j < N) v += deg[g + j];
  s[tid] = v;
  __syncthreads();
  for (int off = TPB / 2; off > 0; off >>= 1) {
    if (tid < off) s[tid] += s[tid + off];
    __syncthreads();
  }
  if (tid == 0) bsum[blockIdx.x] = s[0];
}

__global__ void k_scanb(const int* __restrict__ bsum, int* __restrict__ boff, int NB) {
  if (threadIdx.x == 0) {
    int a = 0;
    for (int i = 0; i < NB; ++i) { boff[i] = a; a += bsum[i]; }
  }
}

__global__ __launch_bounds__(TPB)
void k_apply(const int* __restrict__ deg, const int* __restrict__ boff,
             int* __restrict__ cur, int N) {
  __shared__ int s[TPB];
  const int tid = threadIdx.x;
  const int g = (blockIdx.x * TPB + tid) * 4;
  int d[4];
  int v = 0;
  #pragma unroll
  for (int j = 0; j < 4; ++j) { d[j] = (g + j < N) ? deg[g + j] : 0; v += d[j]; }
  s[tid] = v;
  __syncthreads();
  for (int off = 1; off < TPB; off <<= 1) {
    int t = (tid >= off) ? s[tid - off] : 0;
    __syncthreads();
    s[tid] += t;
    __syncthreads();
  }
  int base = boff[blockIdx.x] + s[tid] - v;
  #pragma unroll
  for (int j = 0; j < 4; ++j)
    if (g + j < N) { cur[g + j] = base; base += d[j]; }
}

// stores {edge id, col} at the CSR slot; col is read COALESCED here so the
// edge kernel never does a random ei[E+e] load.
__global__ __launch_bounds__(TPB)
void k_scatter(const int* __restrict__ ei, int* __restrict__ cur,
               int2* __restrict__ ec, int E) {
  int e = blockIdx.x * TPB + threadIdx.x;
  if (e < E) {
    const int r = ei[e];
    const int c = ei[E + e];
    int p = atomicAdd(&cur[r], 1);
    ec[p] = make_int2(e, c);
  }
}

// ---------------- U/V precompute ----------------

__global__ __launch_bounds__(TPB)
void k_prep2(const float* __restrict__ x,
             const float* __restrict__ ew1, const float* __restrict__ eb1,
             float* __restrict__ U, float* __restrict__ V, int N)
{
  const int t = blockIdx.x * TPB + threadIdx.x;
  const int w = __builtin_amdgcn_readfirstlane(t >> 6);
  const int lane = t & 63;
  const int half = w & 1;
  const int n = (w >> 1) * 64 + lane;
  if (n >= N) return;

  const float* xn = x + (size_t)n * 64;
  const float* W = ew1 + (half ? 64 * 64 : 0);

  float acc[64];
  if (half) {
    #pragma unroll
    for (int c = 0; c < 64; ++c) acc[c] = 0.f;
  } else {
    #pragma unroll
    for (int c = 0; c < 64; ++c) acc[c] = eb1[c];
  }
  SEG_G(xn, 16, 0, W, acc)

  float* dst = (half ? V : U) + (size_t)n * 64;
  float4* d4 = (float4*)dst;
  #pragma unroll
  for (int c4 = 0; c4 < 16; ++c4)
    d4[c4] = make_float4(acc[c4*4+0], acc[c4*4+1], acc[c4*4+2], acc[c4*4+3]);
}

// ---------------- edge phase: wave per node, chunk-of-4 pipeline ----------------

#define EDGE_TERM(EIDX, VV, OUTACC)                                     \
  {                                                                     \
    const float* eap_ = ea + (size_t)(EIDX) * 32;                       \
    float t0_ = u + (VV), t1_ = 0.f, t2_ = 0.f, t3_ = 0.f;              \
    _Pragma("unroll")                                                   \
    for (int k_ = 0; k_ < 32; k_ += 4) {                                \
      t0_ = fmaf(eap_[k_ + 0], w[k_ + 0], t0_);                         \
      t1_ = fmaf(eap_[k_ + 1], w[k_ + 1], t1_);                         \
      t2_ = fmaf(eap_[k_ + 2], w[k_ + 2], t2_);                         \
      t3_ = fmaf(eap_[k_ + 3], w[k_ + 3], t3_);                         \
    }                                                                   \
    OUTACC += fmaxf((t0_ + t1_) + (t2_ + t3_), 0.f);                    \
  }

__global__ __launch_bounds__(TPB)
void k_edge4(const float* __restrict__ U, const float* __restrict__ V,
             const float* __restrict__ ea,
             const float* __restrict__ ew1,
             const int* __restrict__ deg, const int* __restrict__ cur,
             const int2* __restrict__ ec,
             float* __restrict__ H, int N)
{
  const int lane = threadIdx.x & 63;
  const int wid  = __builtin_amdgcn_readfirstlane(threadIdx.x >> 6);
  const int n    = __builtin_amdgcn_readfirstlane((int)blockIdx.x * 4 + wid);
  if (n >= N) return;

  const int d  = __builtin_amdgcn_readfirstlane(deg[n]);
  const int s0 = __builtin_amdgcn_readfirstlane(cur[n]) - d;

  // this lane's W1c column (coalesced, loaded once)
  float w[32];
  #pragma unroll
  for (int k = 0; k < 32; ++k) w[k] = ew1[(128 + k) * 64 + lane];

  const float u = U[(size_t)n * 64 + lane];
  const int2* ecp = ec + s0;          // wave-uniform, sequential -> s_load
  float acc = 0.f;

  int i = 0;
  for (; i + 4 <= d; i += 4) {
    const int e0 = __builtin_amdgcn_readfirstlane(ecp[i + 0].x);
    const int c0 = __builtin_amdgcn_readfirstlane(ecp[i + 0].y);
    const int e1 = __builtin_amdgcn_readfirstlane(ecp[i + 1].x);
    const int c1 = __builtin_amdgcn_readfirstlane(ecp[i + 1].y);
    const int e2 = __builtin_amdgcn_readfirstlane(ecp[i + 2].x);
    const int c2 = __builtin_amdgcn_readfirstlane(ecp[i + 2].y);
    const int e3 = __builtin_amdgcn_readfirstlane(ecp[i + 3].x);
    const int c3 = __builtin_amdgcn_readfirstlane(ecp[i + 3].y);

    // 4 independent V-row loads issued back-to-back (one latency exposure)
    const float v0 = V[(size_t)c0 * 64 + lane];
    const float v1 = V[(size_t)c1 * 64 + lane];
    const float v2 = V[(size_t)c2 * 64 + lane];
    const float v3 = V[(size_t)c3 * 64 + lane];

    EDGE_TERM(e0, v0, acc)
    EDGE_TERM(e1, v1, acc)
    EDGE_TERM(e2, v2, acc)
    EDGE_TERM(e3, v3, acc)
  }
  for (; i < d; ++i) {
    const int e0 = __builtin_amdgcn_readfirstlane(ecp[i].x);
    const int c0 = __builtin_amdgcn_readfirstlane(ecp[i].y);
    const float v0 = V[(size_t)c0 * 64 + lane];
    EDGE_TERM(e0, v0, acc)
  }

  H[(size_t)n * 64 + lane] = acc;
}

// ---------------- node MLP ----------------

__global__ __launch_bounds__(TPB)
void k_node2(const float* __restrict__ x, const float* __restrict__ Hin,
             const int* __restrict__ deg,
             const float* __restrict__ ew2, const float* __restrict__ eb2,
             const float* __restrict__ nw1, const float* __restrict__ nb1,
             const float* __restrict__ nw2, const float* __restrict__ nb2,
             float* __restrict__ out, int N)
{
  __shared__ float hbuf[16 * 257];
  const int tid = threadIdx.x;
  const int n = blockIdx.x * TPB + tid;
  if (n >= N) return;
  float* hcol = hbuf + tid;

  float hrow[64];
  {
    const float4* h4 = (const float4*)(Hin + (size_t)n * 64);
    #pragma unroll
    for (int c4 = 0; c4 < 16; ++c4) {
      const float4 a = h4[c4];
      hrow[c4*4+0] = a.x; hrow[c4*4+1] = a.y; hrow[c4*4+2] = a.z; hrow[c4*4+3] = a.w;
    }
  }
  const float dg = (float)deg[n];

  float agg[64];
  #pragma unroll
  for (int c = 0; c < 64; ++c) agg[c] = dg * eb2[c];
  SEGH(ew2, 0, hrow[q_ * 16 + kk_], agg, hcol)

  float acc[64];
  #pragma unroll
  for (int c = 0; c < 64; ++c) acc[c] = nb1[c];
  SEG_G(x + (size_t)n * 64, 16, 0, nw1, acc)
  SEGH(nw1, 64, agg[q_ * 16 + kk_], acc, hcol)

  float o[64];
  #pragma unroll
  for (int c = 0; c < 64; ++c) o[c] = nb2[c];
  SEGH(nw2, 0, fmaxf(acc[q_ * 16 + kk_], 0.f), o, hcol)

  float4* ov = (float4*)(out + (size_t)n * 64);
  #pragma unroll
  for (int c4 = 0; c4 < 16; ++c4)
    ov[c4] = make_float4(o[c4*4+0], o[c4*4+1], o[c4*4+2], o[c4*4+3]);
}

// ---------------- launch ----------------

extern "C" void kernel_launch(void* const* d_in, const int* in_sizes, int n_in,
                              void* d_out, int out_size, void* d_ws, size_t ws_size,
                              hipStream_t stream) {
  const float* x   = (const float*)d_in[0];
  const int*   ei  = (const int*)d_in[1];
  const float* ea  = (const float*)d_in[2];
  const float* ew1 = (const float*)d_in[3];
  const float* eb1 = (const float*)d_in[4];
  const float* ew2 = (const float*)d_in[5];
  const float* eb2 = (const float*)d_in[6];
  const float* nw1 = (const float*)d_in[7];
  const float* nb1 = (const float*)d_in[8];
  const float* nw2 = (const float*)d_in[9];
  const float* nb2 = (const float*)d_in[10];
  float* out = (float*)d_out;

  const int N = in_sizes[0] / 64;   // 100000
  const int E = in_sizes[1] / 2;    // 1600000

  // workspace layout
  float* U   = (float*)d_ws;                      // N*64 f32
  float* V   = U + (size_t)N * 64;                // N*64 f32
  int* ib    = (int*)(V + (size_t)N * 64);
  int* deg   = ib;                                // N
  int* cur   = ib + N;                            // N
  int* bsum  = ib + 2 * N;                        // <=512
  int* boff  = ib + 2 * N + 512;                  // <=512
  int2* ec   = (int2*)(ib + 2 * N + 1024);        // E int2 (8B-aligned: 2N+1024 even)
  float* H   = out;

  const int NT = (N + 3) / 4;
  const int NB = (NT + TPB - 1) / TPB;

  hipMemsetAsync(deg, 0, (size_t)N * sizeof(int), stream);

  k_hist<<<(E + TPB - 1) / TPB, TPB, 0, stream>>>(ei, deg, E);
  k_red<<<NB, TPB, 0, stream>>>(deg, bsum, N);
  k_scanb<<<1, 64, 0, stream>>>(bsum, boff, NB);
  k_apply<<<NB, TPB, 0, stream>>>(deg, boff, cur, N);
  k_scatter<<<(E + TPB - 1) / TPB, TPB, 0, stream>>>(ei, cur, ec, E);

  {
    const int nwaves = 2 * ((N + 63) / 64);
    const int nblocks = (nwaves + 3) / 4;
    k_prep2<<<nblocks, TPB, 0, stream>>>(x, ew1, eb1, U, V, N);
  }

  k_edge4<<<(N + 3) / 4, TPB, 0, stream>>>(
      U, V, ea, ew1, deg, cur, ec, H, N);

  k_node2<<<(N + TPB - 1) / TPB, TPB, 0, stream>>>(
      x, H, deg, ew2, eb2, nw1, nb1, nw2, nb2, out, N);
}

// Round 7
// 560.010 us; speedup vs baseline: 1.1664x; 1.1664x over previous
//
#include <hip/hip_runtime.h>
#include <hip/hip_bf16.h>

// GraphMatchingLayer, round 7:
//  - k_edge5: ea rows fetched via VECTOR path (coalesced 8-lane groups) into a
//    wave-private LDS strip, then broadcast ds_read_b128 -> no scalar-cache
//    serialization (round 5/6's hidden cap). 8-edge software-pipelined chunks,
//    V rows issued up front via v_readlane'd columns.
//  - CSR build / k_prep2 / k_node2 unchanged from round 6.

#define TPB 256

#define SEG_G(SRC, NCH, KB, W, ACC)                                     \
  for (int kc_ = 0; kc_ < (NCH); ++kc_) {                               \
    const float4 a_ = ((const float4*)(SRC))[kc_];                      \
    const float av_[4] = {a_.x, a_.y, a_.z, a_.w};                      \
    _Pragma("unroll")                                                   \
    for (int j_ = 0; j_ < 4; ++j_) {                                    \
      const float ak_ = av_[j_];                                        \
      const float* wr_ = (W) + ((KB) + kc_ * 4 + j_) * 64;              \
      _Pragma("unroll")                                                 \
      for (int cc_ = 0; cc_ < 64; ++cc_)                                \
        ACC[cc_] = fmaf(ak_, wr_[cc_], ACC[cc_]);                       \
    }                                                                   \
  }

#define SEGH(W, KB, SRCEXPR, ACC, HCOL)                                 \
  _Pragma("unroll")                                                     \
  for (int q_ = 0; q_ < 4; ++q_) {                                      \
    _Pragma("unroll")                                                   \
    for (int kk_ = 0; kk_ < 16; ++kk_)                                  \
      (HCOL)[kk_ * 257] = (SRCEXPR);                                    \
    for (int kk_ = 0; kk_ < 16; ++kk_) {                                \
      const float ak_ = (HCOL)[kk_ * 257];                              \
      const float* wr_ = (W) + ((KB) + q_ * 16 + kk_) * 64;             \
      _Pragma("unroll")                                                 \
      for (int cc_ = 0; cc_ < 64; ++cc_)                                \
        ACC[cc_] = fmaf(ak_, wr_[cc_], ACC[cc_]);                       \
    }                                                                   \
  }

// ---------------- CSR build ----------------

__global__ __launch_bounds__(TPB)
void k_hist(const int* __restrict__ ei, int* __restrict__ deg, int E) {
  int e = blockIdx.x * TPB + threadIdx.x;
  if (e < E) atomicAdd(&deg[ei[e]], 1);
}

__global__ __launch_bounds__(TPB)
void k_red(const int* __restrict__ deg, int* __restrict__ bsum, int N) {
  __shared__ int s[TPB];
  const int tid = threadIdx.x;
  const int g = (blockIdx.x * TPB + tid) * 4;
  int v = 0;
  #pragma unroll
  for (int j = 0; j < 4; ++j) if (g + j < N) v += deg[g + j];
  s[tid] = v;
  __syncthreads();
  for (int off = TPB / 2; off > 0; off >>= 1) {
    if (tid < off) s[tid] += s[tid + off];
    __syncthreads();
  }
  if (tid == 0) bsum[blockIdx.x] = s[0];
}

__global__ void k_scanb(const int* __restrict__ bsum, int* __restrict__ boff, int NB) {
  if (threadIdx.x == 0) {
    int a = 0;
    for (int i = 0; i < NB; ++i) { boff[i] = a; a += bsum[i]; }
  }
}

__global__ __launch_bounds__(TPB)
void k_apply(const int* __restrict__ deg, const int* __restrict__ boff,
             int* __restrict__ cur, int N) {
  __shared__ int s[TPB];
  const int tid = threadIdx.x;
  const int g = (blockIdx.x * TPB + tid) * 4;
  int d[4];
  int v = 0;
  #pragma unroll
  for (int j = 0; j < 4; ++j) { d[j] = (g + j < N) ? deg[g + j] : 0; v += d[j]; }
  s[tid] = v;
  __syncthreads();
  for (int off = 1; off < TPB; off <<= 1) {
    int t = (tid >= off) ? s[tid - off] : 0;
    __syncthreads();
    s[tid] += t;
    __syncthreads();
  }
  int base = boff[blockIdx.x] + s[tid] - v;
  #pragma unroll
  for (int j = 0; j < 4; ++j)
    if (g + j < N) { cur[g + j] = base; base += d[j]; }
}

__global__ __launch_bounds__(TPB)
void k_scatter(const int* __restrict__ ei, int* __restrict__ cur,
               int2* __restrict__ ec, int E) {
  int e = blockIdx.x * TPB + threadIdx.x;
  if (e < E) {
    const int r = ei[e];
    const int c = ei[E + e];
    int p = atomicAdd(&cur[r], 1);
    ec[p] = make_int2(e, c);
  }
}

// ---------------- U/V precompute ----------------

__global__ __launch_bounds__(TPB)
void k_prep2(const float* __restrict__ x,
             const float* __restrict__ ew1, const float* __restrict__ eb1,
             float* __restrict__ U, float* __restrict__ V, int N)
{
  const int t = blockIdx.x * TPB + threadIdx.x;
  const int w = __builtin_amdgcn_readfirstlane(t >> 6);
  const int lane = t & 63;
  const int half = w & 1;
  const int n = (w >> 1) * 64 + lane;
  if (n >= N) return;

  const float* xn = x + (size_t)n * 64;
  const float* W = ew1 + (half ? 64 * 64 : 0);

  float acc[64];
  if (half) {
    #pragma unroll
    for (int c = 0; c < 64; ++c) acc[c] = 0.f;
  } else {
    #pragma unroll
    for (int c = 0; c < 64; ++c) acc[c] = eb1[c];
  }
  SEG_G(xn, 16, 0, W, acc)

  float* dst = (half ? V : U) + (size_t)n * 64;
  float4* d4 = (float4*)dst;
  #pragma unroll
  for (int c4 = 0; c4 < 16; ++c4)
    d4[c4] = make_float4(acc[c4*4+0], acc[c4*4+1], acc[c4*4+2], acc[c4*4+3]);
}

// ---------------- edge phase: wave/node, LDS-broadcast ea, 8-edge chunks ----------------

__global__ __launch_bounds__(TPB)
void k_edge5(const float* __restrict__ U, const float* __restrict__ V,
             const float* __restrict__ ea,
             const float* __restrict__ ew1,
             const int* __restrict__ deg, const int* __restrict__ cur,
             const int2* __restrict__ ec,
             float* __restrict__ H, int N)
{
  // wave-private strips: 8 edges x 32 floats per wave
  __shared__ float sbuf[4 * 8 * 32];

  const int lane = threadIdx.x & 63;
  const int wid  = __builtin_amdgcn_readfirstlane(threadIdx.x >> 6);
  const int n    = __builtin_amdgcn_readfirstlane((int)blockIdx.x * 4 + wid);
  if (n >= N) return;

  const int d  = __builtin_amdgcn_readfirstlane(deg[n]);
  const int s0 = __builtin_amdgcn_readfirstlane(cur[n]) - d;

  float* lw = sbuf + wid * 256;          // this wave's 1KB strip
  const int g = lane >> 3;               // which edge of the chunk this lane helps load
  const int o = lane & 7;                // float4 slot within the 32-float row

  // this lane's W1c column (coalesced, loaded once)
  float w[32];
  #pragma unroll
  for (int k = 0; k < 32; ++k) w[k] = ew1[(128 + k) * 64 + lane];

  const float u = U[(size_t)n * 64 + lane];
  const int2* ecp = ec + s0;
  float acc = 0.f;

  for (int i = 0; i < d; i += 8) {
    const int rem = d - i;               // >= 1, uniform
    const int gg = (g < rem) ? g : rem - 1;

    // per-lane {edge,col} (sequential region, L1-hot); 8-lane broadcast groups
    const int2 ecv = ecp[i + gg];

    // ea row -> LDS via the VECTOR path (8 random 128B rows, coalesced per group)
    const float4 eav = *(const float4*)(ea + (size_t)ecv.x * 32 + o * 4);

    // 8 V-row loads issued up front (columns broadcast via readlane)
    const int c0 = __builtin_amdgcn_readlane(ecv.y, 0);
    const int c1 = __builtin_amdgcn_readlane(ecv.y, 8);
    const int c2 = __builtin_amdgcn_readlane(ecv.y, 16);
    const int c3 = __builtin_amdgcn_readlane(ecv.y, 24);
    const int c4 = __builtin_amdgcn_readlane(ecv.y, 32);
    const int c5 = __builtin_amdgcn_readlane(ecv.y, 40);
    const int c6 = __builtin_amdgcn_readlane(ecv.y, 48);
    const int c7 = __builtin_amdgcn_readlane(ecv.y, 56);
    const float v0 = V[(size_t)c0 * 64 + lane];
    const float v1 = V[(size_t)c1 * 64 + lane];
    const float v2 = V[(size_t)c2 * 64 + lane];
    const float v3 = V[(size_t)c3 * 64 + lane];
    const float v4 = V[(size_t)c4 * 64 + lane];
    const float v5 = V[(size_t)c5 * 64 + lane];
    const float v6 = V[(size_t)c6 * 64 + lane];
    const float v7 = V[(size_t)c7 * 64 + lane];

    *(float4*)(lw + lane * 4) = eav;     // ds_write_b128 (compiler waits vmcnt for eav)
    asm volatile("s_waitcnt lgkmcnt(0)" ::: "memory");  // strip ready for this wave

    const float vs[8] = {v0, v1, v2, v3, v4, v5, v6, v7};
    #pragma unroll
    for (int j = 0; j < 8; ++j) {
      const float* er = lw + j * 32;     // uniform addr -> broadcast ds_read_b128
      float t0 = u, t1 = 0.f, t2 = 0.f, t3 = 0.f;
      #pragma unroll
      for (int k = 0; k < 32; k += 4) {
        t0 = fmaf(er[k + 0], w[k + 0], t0);
        t1 = fmaf(er[k + 1], w[k + 1], t1);
        t2 = fmaf(er[k + 2], w[k + 2], t2);
        t3 = fmaf(er[k + 3], w[k + 3], t3);
      }
      const float s = fmaxf(((t0 + t1) + (t2 + t3)) + vs[j], 0.f);
      acc += (j < rem) ? s : 0.f;
    }
  }

  H[(size_t)n * 64 + lane] = acc;
}

// ---------------- node MLP ----------------

__global__ __launch_bounds__(TPB)
void k_node2(const float* __restrict__ x, const float* __restrict__ Hin,
             const int* __restrict__ deg,
             const float* __restrict__ ew2, const float* __restrict__ eb2,
             const float* __restrict__ nw1, const float* __restrict__ nb1,
             const float* __restrict__ nw2, const float* __restrict__ nb2,
             float* __restrict__ out, int N)
{
  __shared__ float hbuf[16 * 257];
  const int tid = threadIdx.x;
  const int n = blockIdx.x * TPB + tid;
  if (n >= N) return;
  float* hcol = hbuf + tid;

  float hrow[64];
  {
    const float4* h4 = (const float4*)(Hin + (size_t)n * 64);
    #pragma unroll
    for (int c4 = 0; c4 < 16; ++c4) {
      const float4 a = h4[c4];
      hrow[c4*4+0] = a.x; hrow[c4*4+1] = a.y; hrow[c4*4+2] = a.z; hrow[c4*4+3] = a.w;
    }
  }
  const float dg = (float)deg[n];

  float agg[64];
  #pragma unroll
  for (int c = 0; c < 64; ++c) agg[c] = dg * eb2[c];
  SEGH(ew2, 0, hrow[q_ * 16 + kk_], agg, hcol)

  float acc[64];
  #pragma unroll
  for (int c = 0; c < 64; ++c) acc[c] = nb1[c];
  SEG_G(x + (size_t)n * 64, 16, 0, nw1, acc)
  SEGH(nw1, 64, agg[q_ * 16 + kk_], acc, hcol)

  float o[64];
  #pragma unroll
  for (int c = 0; c < 64; ++c) o[c] = nb2[c];
  SEGH(nw2, 0, fmaxf(acc[q_ * 16 + kk_], 0.f), o, hcol)

  float4* ov = (float4*)(out + (size_t)n * 64);
  #pragma unroll
  for (int c4 = 0; c4 < 16; ++c4)
    ov[c4] = make_float4(o[c4*4+0], o[c4*4+1], o[c4*4+2], o[c4*4+3]);
}

// ---------------- launch ----------------

extern "C" void kernel_launch(void* const* d_in, const int* in_sizes, int n_in,
                              void* d_out, int out_size, void* d_ws, size_t ws_size,
                              hipStream_t stream) {
  const float* x   = (const float*)d_in[0];
  const int*   ei  = (const int*)d_in[1];
  const float* ea  = (const float*)d_in[2];
  const float* ew1 = (const float*)d_in[3];
  const float* eb1 = (const float*)d_in[4];
  const float* ew2 = (const float*)d_in[5];
  const float* eb2 = (const float*)d_in[6];
  const float* nw1 = (const float*)d_in[7];
  const float* nb1 = (const float*)d_in[8];
  const float* nw2 = (const float*)d_in[9];
  const float* nb2 = (const float*)d_in[10];
  float* out = (float*)d_out;

  const int N = in_sizes[0] / 64;   // 100000
  const int E = in_sizes[1] / 2;    // 1600000

  // workspace layout
  float* U   = (float*)d_ws;                      // N*64 f32
  float* V   = U + (size_t)N * 64;                // N*64 f32
  int* ib    = (int*)(V + (size_t)N * 64);
  int* deg   = ib;                                // N
  int* cur   = ib + N;                            // N
  int* bsum  = ib + 2 * N;                        // <=512
  int* boff  = ib + 2 * N + 512;                  // <=512
  int2* ec   = (int2*)(ib + 2 * N + 1024);        // E int2
  float* H   = out;

  const int NT = (N + 3) / 4;
  const int NB = (NT + TPB - 1) / TPB;

  hipMemsetAsync(deg, 0, (size_t)N * sizeof(int), stream);

  k_hist<<<(E + TPB - 1) / TPB, TPB, 0, stream>>>(ei, deg, E);
  k_red<<<NB, TPB, 0, stream>>>(deg, bsum, N);
  k_scanb<<<1, 64, 0, stream>>>(bsum, boff, NB);
  k_apply<<<NB, TPB, 0, stream>>>(deg, boff, cur, N);
  k_scatter<<<(E + TPB - 1) / TPB, TPB, 0, stream>>>(ei, cur, ec, E);

  {
    const int nwaves = 2 * ((N + 63) / 64);
    const int nblocks = (nwaves + 3) / 4;
    k_prep2<<<nblocks, TPB, 0, stream>>>(x, ew1, eb1, U, V, N);
  }

  k_edge5<<<(N + 3) / 4, TPB, 0, stream>>>(
      U, V, ea, ew1, deg, cur, ec, H, N);

  k_node2<<<(N + TPB - 1) / TPB, TPB, 0, stream>>>(
      x, H, deg, ew2, eb2, nw1, nb1, nw2, nb2, out, N);
}

// Round 8
// 482.251 us; speedup vs baseline: 1.3544x; 1.1612x over previous
//
#include <hip/hip_runtime.h>
#include <hip/hip_bf16.h>

// GraphMatchingLayer, round 8:
//  - k_edge5 FROZEN from round 7 (218 us, VALU 84%).
//  - k_node3: two half-waves per node group (channel split h=0/32), LDS row
//    exchange (stride-65, conflict-free), 3 barriers, no hcol, 2x waves.
//  - k_prep3: 4-way wave split (U/V x channel-half) -> 6252 waves.
//  - k_scanb: one-wave shfl scan instead of single-thread serial loop.

#define TPB 256

#define SEG_G(SRC, NCH, KB, W, ACC)                                     \
  for (int kc_ = 0; kc_ < (NCH); ++kc_) {                               \
    const float4 a_ = ((const float4*)(SRC))[kc_];                      \
    const float av_[4] = {a_.x, a_.y, a_.z, a_.w};                      \
    _Pragma("unroll")                                                   \
    for (int j_ = 0; j_ < 4; ++j_) {                                    \
      const float ak_ = av_[j_];                                        \
      const float* wr_ = (W) + ((KB) + kc_ * 4 + j_) * 64;              \
      _Pragma("unroll")                                                 \
      for (int cc_ = 0; cc_ < 64; ++cc_)                                \
        ACC[cc_] = fmaf(ak_, wr_[cc_], ACC[cc_]);                       \
    }                                                                   \
  }

// 32-wide variant: accumulate 32 output channels starting at column COL
#define SEG32(SRC, NCH, KB, W, COL, ACC)                                \
  for (int kc_ = 0; kc_ < (NCH); ++kc_) {                               \
    const float4 a_ = ((const float4*)(SRC))[kc_];                      \
    const float av_[4] = {a_.x, a_.y, a_.z, a_.w};                      \
    _Pragma("unroll")                                                   \
    for (int j_ = 0; j_ < 4; ++j_) {                                    \
      const float ak_ = av_[j_];                                        \
      const float* wr_ = (W) + ((KB) + kc_ * 4 + j_) * 64 + (COL);      \
      _Pragma("unroll")                                                 \
      for (int cc_ = 0; cc_ < 32; ++cc_)                                \
        ACC[cc_] = fmaf(ak_, wr_[cc_], ACC[cc_]);                       \
    }                                                                   \
  }

// ---------------- CSR build ----------------

__global__ __launch_bounds__(TPB)
void k_hist(const int* __restrict__ ei, int* __restrict__ deg, int E) {
  int e = blockIdx.x * TPB + threadIdx.x;
  if (e < E) atomicAdd(&deg[ei[e]], 1);
}

__global__ __launch_bounds__(TPB)
void k_red(const int* __restrict__ deg, int* __restrict__ bsum, int N) {
  __shared__ int s[TPB];
  const int tid = threadIdx.x;
  const int g = (blockIdx.x * TPB + tid) * 4;
  int v = 0;
  #pragma unroll
  for (int j = 0; j < 4; ++j) if (g + j < N) v += deg[g + j];
  s[tid] = v;
  __syncthreads();
  for (int off = TPB / 2; off > 0; off >>= 1) {
    if (tid < off) s[tid] += s[tid + off];
    __syncthreads();
  }
  if (tid == 0) bsum[blockIdx.x] = s[0];
}

// one-wave shfl prefix scan (NB <= 128)
__global__ __launch_bounds__(64)
void k_scanb(const int* __restrict__ bsum, int* __restrict__ boff, int NB) {
  const int lane = threadIdx.x;
  const int a = (2 * lane     < NB) ? bsum[2 * lane]     : 0;
  const int b = (2 * lane + 1 < NB) ? bsum[2 * lane + 1] : 0;
  int s = a + b;
  #pragma unroll
  for (int off = 1; off < 64; off <<= 1) {
    const int t = __shfl_up(s, off);
    if (lane >= off) s += t;
  }
  const int excl = s - (a + b);
  if (2 * lane     < NB) boff[2 * lane]     = excl;
  if (2 * lane + 1 < NB) boff[2 * lane + 1] = excl + a;
}

__global__ __launch_bounds__(TPB)
void k_apply(const int* __restrict__ deg, const int* __restrict__ boff,
             int* __restrict__ cur, int N) {
  __shared__ int s[TPB];
  const int tid = threadIdx.x;
  const int g = (blockIdx.x * TPB + tid) * 4;
  int d[4];
  int v = 0;
  #pragma unroll
  for (int j = 0; j < 4; ++j) { d[j] = (g + j < N) ? deg[g + j] : 0; v += d[j]; }
  s[tid] = v;
  __syncthreads();
  for (int off = 1; off < TPB; off <<= 1) {
    int t = (tid >= off) ? s[tid - off] : 0;
    __syncthreads();
    s[tid] += t;
    __syncthreads();
  }
  int base = boff[blockIdx.x] + s[tid] - v;
  #pragma unroll
  for (int j = 0; j < 4; ++j)
    if (g + j < N) { cur[g + j] = base; base += d[j]; }
}

__global__ __launch_bounds__(TPB)
void k_scatter(const int* __restrict__ ei, int* __restrict__ cur,
               int2* __restrict__ ec, int E) {
  int e = blockIdx.x * TPB + threadIdx.x;
  if (e < E) {
    const int r = ei[e];
    const int c = ei[E + e];
    int p = atomicAdd(&cur[r], 1);
    ec[p] = make_int2(e, c);
  }
}

// ---------------- U/V precompute: 4-way wave split ----------------
// wave q=0..3 within node group: uv = q>>1 (U or V), col half = (q&1)*32

__global__ __launch_bounds__(TPB)
void k_prep3(const float* __restrict__ x,
             const float* __restrict__ ew1, const float* __restrict__ eb1,
             float* __restrict__ U, float* __restrict__ V, int N)
{
  const int t = blockIdx.x * TPB + threadIdx.x;
  const int wv = __builtin_amdgcn_readfirstlane(t >> 6);
  const int lane = t & 63;
  const int q = wv & 3;
  const int n = (wv >> 2) * 64 + lane;
  if (n >= N) return;

  const int uv = q >> 1;
  const int h = (q & 1) * 32;
  const float* W = ew1 + uv * 64 * 64;

  float acc[32];
  if (uv) {
    #pragma unroll
    for (int j = 0; j < 32; ++j) acc[j] = 0.f;
  } else {
    #pragma unroll
    for (int j = 0; j < 32; ++j) acc[j] = eb1[h + j];
  }
  SEG32(x + (size_t)n * 64, 16, 0, W, h, acc)

  float* dst = (uv ? V : U) + (size_t)n * 64 + h;
  float4* d4 = (float4*)dst;
  #pragma unroll
  for (int c4 = 0; c4 < 8; ++c4)
    d4[c4] = make_float4(acc[c4*4+0], acc[c4*4+1], acc[c4*4+2], acc[c4*4+3]);
}

// ---------------- edge phase (FROZEN, round 7) ----------------

__global__ __launch_bounds__(TPB)
void k_edge5(const float* __restrict__ U, const float* __restrict__ V,
             const float* __restrict__ ea,
             const float* __restrict__ ew1,
             const int* __restrict__ deg, const int* __restrict__ cur,
             const int2* __restrict__ ec,
             float* __restrict__ H, int N)
{
  __shared__ float sbuf[4 * 8 * 32];

  const int lane = threadIdx.x & 63;
  const int wid  = __builtin_amdgcn_readfirstlane(threadIdx.x >> 6);
  const int n    = __builtin_amdgcn_readfirstlane((int)blockIdx.x * 4 + wid);
  if (n >= N) return;

  const int d  = __builtin_amdgcn_readfirstlane(deg[n]);
  const int s0 = __builtin_amdgcn_readfirstlane(cur[n]) - d;

  float* lw = sbuf + wid * 256;
  const int g = lane >> 3;
  const int o = lane & 7;

  float w[32];
  #pragma unroll
  for (int k = 0; k < 32; ++k) w[k] = ew1[(128 + k) * 64 + lane];

  const float u = U[(size_t)n * 64 + lane];
  const int2* ecp = ec + s0;
  float acc = 0.f;

  for (int i = 0; i < d; i += 8) {
    const int rem = d - i;
    const int gg = (g < rem) ? g : rem - 1;

    const int2 ecv = ecp[i + gg];
    const float4 eav = *(const float4*)(ea + (size_t)ecv.x * 32 + o * 4);

    const int c0 = __builtin_amdgcn_readlane(ecv.y, 0);
    const int c1 = __builtin_amdgcn_readlane(ecv.y, 8);
    const int c2 = __builtin_amdgcn_readlane(ecv.y, 16);
    const int c3 = __builtin_amdgcn_readlane(ecv.y, 24);
    const int c4 = __builtin_amdgcn_readlane(ecv.y, 32);
    const int c5 = __builtin_amdgcn_readlane(ecv.y, 40);
    const int c6 = __builtin_amdgcn_readlane(ecv.y, 48);
    const int c7 = __builtin_amdgcn_readlane(ecv.y, 56);
    const float v0 = V[(size_t)c0 * 64 + lane];
    const float v1 = V[(size_t)c1 * 64 + lane];
    const float v2 = V[(size_t)c2 * 64 + lane];
    const float v3 = V[(size_t)c3 * 64 + lane];
    const float v4 = V[(size_t)c4 * 64 + lane];
    const float v5 = V[(size_t)c5 * 64 + lane];
    const float v6 = V[(size_t)c6 * 64 + lane];
    const float v7 = V[(size_t)c7 * 64 + lane];

    *(float4*)(lw + lane * 4) = eav;
    asm volatile("s_waitcnt lgkmcnt(0)" ::: "memory");

    const float vs[8] = {v0, v1, v2, v3, v4, v5, v6, v7};
    #pragma unroll
    for (int j = 0; j < 8; ++j) {
      const float* er = lw + j * 32;
      float t0 = u, t1 = 0.f, t2 = 0.f, t3 = 0.f;
      #pragma unroll
      for (int k = 0; k < 32; k += 4) {
        t0 = fmaf(er[k + 0], w[k + 0], t0);
        t1 = fmaf(er[k + 1], w[k + 1], t1);
        t2 = fmaf(er[k + 2], w[k + 2], t2);
        t3 = fmaf(er[k + 3], w[k + 3], t3);
      }
      const float s = fmaxf(((t0 + t1) + (t2 + t3)) + vs[j], 0.f);
      acc += (j < rem) ? s : 0.f;
    }
  }

  H[(size_t)n * 64 + lane] = acc;
}

// ---------------- node MLP: two half-waves per node group ----------------
// block = 256 threads = 2 node groups x 2 channel halves.
// sb row stride 65 floats -> column access (fixed k, lanes vary) conflict-free.

__global__ __launch_bounds__(TPB)
void k_node3(const float* __restrict__ x, const float* __restrict__ Hin,
             const int* __restrict__ deg,
             const float* __restrict__ ew2, const float* __restrict__ eb2,
             const float* __restrict__ nw1, const float* __restrict__ nb1,
             const float* __restrict__ nw2, const float* __restrict__ nb2,
             float* __restrict__ out, int N)
{
  __shared__ float sb[2][64 * 65];          // 33.3 KB

  const int tid  = threadIdx.x;
  const int wv   = __builtin_amdgcn_readfirstlane(tid >> 6);
  const int lane = tid & 63;
  const int grp  = wv >> 1;
  const int h    = (wv & 1) * 32;           // wave-uniform channel half

  const int n  = blockIdx.x * 128 + grp * 64 + lane;
  const bool valid = (n < N);
  const int nn = valid ? n : (N - 1);       // clamp for loads; store guarded

  float* srow = &sb[grp][lane * 65];

  // ---- stage A: agg[h..h+32) = deg*eb2 + H[n] @ ew2 ----
  float acc[32];
  const float dg = (float)deg[nn];
  #pragma unroll
  for (int j = 0; j < 32; ++j) acc[j] = dg * eb2[h + j];
  SEG32(Hin + (size_t)nn * 64, 16, 0, ew2, h, acc)

  #pragma unroll
  for (int j = 0; j < 32; ++j) srow[h + j] = acc[j];
  __syncthreads();

  // ---- stage B: nacc = nb1 + x[n]@nw1[0:64] + agg@nw1[64:128] ----
  float bcc[32];
  #pragma unroll
  for (int j = 0; j < 32; ++j) bcc[j] = nb1[h + j];
  SEG32(x + (size_t)nn * 64, 16, 0, nw1, h, bcc)
  for (int k = 0; k < 64; ++k) {
    const float ak = srow[k];               // ds_read_b32, conflict-free
    const float* wr = nw1 + (64 + k) * 64 + h;
    #pragma unroll
    for (int cc = 0; cc < 32; ++cc) bcc[cc] = fmaf(ak, wr[cc], bcc[cc]);
  }
  __syncthreads();                          // all stage-A reads done

  #pragma unroll
  for (int j = 0; j < 32; ++j) srow[h + j] = fmaxf(bcc[j], 0.f);
  __syncthreads();

  // ---- stage C: out = nb2 + relu(nacc) @ nw2 ----
  float occ[32];
  #pragma unroll
  for (int j = 0; j < 32; ++j) occ[j] = nb2[h + j];
  for (int k = 0; k < 64; ++k) {
    const float ak = srow[k];
    const float* wr = nw2 + k * 64 + h;
    #pragma unroll
    for (int cc = 0; cc < 32; ++cc) occ[cc] = fmaf(ak, wr[cc], occ[cc]);
  }

  if (valid) {
    float4* ov = (float4*)(out + (size_t)n * 64 + h);
    #pragma unroll
    for (int c4 = 0; c4 < 8; ++c4)
      ov[c4] = make_float4(occ[c4*4+0], occ[c4*4+1], occ[c4*4+2], occ[c4*4+3]);
  }
}

// ---------------- launch ----------------

extern "C" void kernel_launch(void* const* d_in, const int* in_sizes, int n_in,
                              void* d_out, int out_size, void* d_ws, size_t ws_size,
                              hipStream_t stream) {
  const float* x   = (const float*)d_in[0];
  const int*   ei  = (const int*)d_in[1];
  const float* ea  = (const float*)d_in[2];
  const float* ew1 = (const float*)d_in[3];
  const float* eb1 = (const float*)d_in[4];
  const float* ew2 = (const float*)d_in[5];
  const float* eb2 = (const float*)d_in[6];
  const float* nw1 = (const float*)d_in[7];
  const float* nb1 = (const float*)d_in[8];
  const float* nw2 = (const float*)d_in[9];
  const float* nb2 = (const float*)d_in[10];
  float* out = (float*)d_out;

  const int N = in_sizes[0] / 64;   // 100000
  const int E = in_sizes[1] / 2;    // 1600000

  // workspace layout
  float* U   = (float*)d_ws;                      // N*64 f32
  float* V   = U + (size_t)N * 64;                // N*64 f32
  int* ib    = (int*)(V + (size_t)N * 64);
  int* deg   = ib;                                // N
  int* cur   = ib + N;                            // N
  int* bsum  = ib + 2 * N;                        // <=512
  int* boff  = ib + 2 * N + 512;                  // <=512
  int2* ec   = (int2*)(ib + 2 * N + 1024);        // E int2
  float* H   = out;

  const int NT = (N + 3) / 4;
  const int NB = (NT + TPB - 1) / TPB;            // 98

  hipMemsetAsync(deg, 0, (size_t)N * sizeof(int), stream);

  k_hist<<<(E + TPB - 1) / TPB, TPB, 0, stream>>>(ei, deg, E);
  k_red<<<NB, TPB, 0, stream>>>(deg, bsum, N);
  k_scanb<<<1, 64, 0, stream>>>(bsum, boff, NB);
  k_apply<<<NB, TPB, 0, stream>>>(deg, boff, cur, N);
  k_scatter<<<(E + TPB - 1) / TPB, TPB, 0, stream>>>(ei, cur, ec, E);

  {
    const int nwaves = 4 * ((N + 63) / 64);
    const int nblocks = (nwaves + 3) / 4;
    k_prep3<<<nblocks, TPB, 0, stream>>>(x, ew1, eb1, U, V, N);
  }

  k_edge5<<<(N + 3) / 4, TPB, 0, stream>>>(
      U, V, ea, ew1, deg, cur, ec, H, N);

  k_node3<<<(N + 127) / 128, TPB, 0, stream>>>(
      x, H, deg, ew2, eb2, nw1, nb1, nw2, nb2, out, N);
}